// Round 3
// baseline (750.915 us; speedup 1.0000x reference)
//
#include <hip/hip_runtime.h>

#define BATCH 4
#define CH    192
#define PLANE 65536

typedef unsigned short u16;
typedef unsigned char  u8;
typedef __bf16 bf16x8_t __attribute__((ext_vector_type(8)));
typedef unsigned short u16x8 __attribute__((ext_vector_type(8)));
typedef unsigned short u16x4 __attribute__((ext_vector_type(4)));
typedef float f32x4 __attribute__((ext_vector_type(4)));

__device__ __forceinline__ u16 f2bf(float f) {
  unsigned u = __builtin_bit_cast(unsigned, f);
  return (u16)((u + 0x7FFFu + ((u >> 16) & 1u)) >> 16);
}
__device__ __forceinline__ float bf2f(u16 h) {
  unsigned u = ((unsigned)h) << 16;
  return __builtin_bit_cast(float, u);
}
__device__ __forceinline__ f32x4 mfma16(u16x8 a, u16x8 b, f32x4 c) {
  return __builtin_amdgcn_mfma_f32_16x16x32_bf16(
      __builtin_bit_cast(bf16x8_t, a), __builtin_bit_cast(bf16x8_t, b), c, 0, 0, 0);
}

// ---- per-(b,c) instance-norm stats for x ----
__global__ void stats_kernel(const float* __restrict__ in, float* __restrict__ st) {
  const int plane = blockIdx.x;
  const float4* p = (const float4*)(in + (long)plane * PLANE);
  float s = 0.f, ss = 0.f;
  for (int i = threadIdx.x; i < PLANE/4; i += 256) {
    float4 v = p[i];
    s  += v.x + v.y + v.z + v.w;
    ss += v.x*v.x + v.y*v.y + v.z*v.z + v.w*v.w;
  }
  for (int off = 1; off < 64; off <<= 1) {
    s  += __shfl_xor(s,  off, 64);
    ss += __shfl_xor(ss, off, 64);
  }
  __shared__ float aux[4][2];
  const int w = threadIdx.x >> 6;
  if ((threadIdx.x & 63) == 0) { aux[w][0] = s; aux[w][1] = ss; }
  __syncthreads();
  if (threadIdx.x == 0) {
    float S  = aux[0][0]+aux[1][0]+aux[2][0]+aux[3][0];
    float SS = aux[0][1]+aux[1][1]+aux[2][1]+aux[3][1];
    float mean = S * (1.f/PLANE);
    float var  = SS * (1.f/PLANE) - mean*mean;
    st[plane*2]   = mean;
    st[plane*2+1] = rsqrtf(var + 1e-5f);
  }
}

__global__ void zero_kernel(float* __restrict__ p) {
  p[blockIdx.x*256 + threadIdx.x] = 0.f;
}

// ---- weight bf16 conversion + bias u8 fixed-point quant ----
__global__ void cvt_kernel(const float* __restrict__ a, const float* __restrict__ b,
                           const float* __restrict__ rb,
                           u16* __restrict__ wa, u16* __restrict__ wb, u8* __restrict__ bq) {
  const int i = blockIdx.x*256 + threadIdx.x;
  if (i < 576*192) wa[i] = f2bf(a[i]);
  if (i < 192*192) wb[i] = f2bf(b[i]);
  if (i < 1350) {
    float v = fminf(fmaxf(rintf(rb[i]*128.f) + 128.f, 0.f), 255.f);
    bq[i] = (u8)v;
  }
}

__global__ void film_prep(const float* __restrict__ cond, const float* __restrict__ fw,
                          const float* __restrict__ fb, float* __restrict__ gb) {
  const int i = blockIdx.x*256 + threadIdx.x;
  if (i >= BATCH*384) return;
  const int bb = i / 384, oc = i - bb*384;
  const float* cw = fw + oc*128;
  const float* cv = cond + bb*128;
  float s = fb[oc];
  for (int k = 0; k < 128; ++k) s += cv[k]*cw[k];
  gb[i] = s;
}

// ---- prep: normalize + window-partition x -> Xn [wid][tok][192c] bf16 ----
// block = (b, wh, c-chunk32): full-row reads, window-major writes (all full-line)
__global__ __launch_bounds__(256) void prep_kernel(
    const float* __restrict__ x, const float* __restrict__ st, u16* __restrict__ xn)
{
  __shared__ u16 tile[32*264];
  const int t = threadIdx.x;
  const int bid = blockIdx.x;
  const int cc = bid % 6;
  const int wh = (bid/6) % 32;
  const int b  = bid / 192;
  const int c0 = cc*32;
  const int ww = t >> 3, ax = t & 7;
  const int gx = (ww*8 + ax + 4) & 255;
  const int gxb = gx & ~3, gxr = gx & 3;
  const long wid = b*1024 + wh*32 + ww;

  for (int ay = 0; ay < 8; ++ay) {
    const int gy = (wh*8 + ay + 4) & 255;
    for (int it = 0; it < 8; ++it) {
      const int id = it*256 + t;
      const int cl = id >> 6;
      const int px = (id & 63) << 2;
      const int c  = c0 + cl;
      const float m = st[(b*192+c)*2], r = st[(b*192+c)*2+1];
      float4 v = *(const float4*)(x + (((long)(b*192+c)) << 16) + gy*256 + px);
      u16x4 pk;
      pk[0] = f2bf((v.x-m)*r); pk[1] = f2bf((v.y-m)*r);
      pk[2] = f2bf((v.z-m)*r); pk[3] = f2bf((v.w-m)*r);
      *(u16x4*)&tile[cl*264 + (px ^ ((cl&7)<<2))] = pk;
    }
    __syncthreads();
    u16* dst = xn + wid*12288 + (ay*8+ax)*192 + c0;
    for (int k = 0; k < 4; ++k) {
      u16x8 pk;
      #pragma unroll
      for (int e = 0; e < 8; ++e) {
        const int c = k*8 + e;
        pk[e] = tile[c*264 + (gxb ^ ((c&7)<<2)) + gxr];
      }
      *(u16x8*)(dst + k*8) = pk;
    }
    __syncthreads();
  }
}

// ---- fused window attention: bf16 window-major in/out, 3 blocks/CU ----
// LDS: Xs [64][200] @0 (25600)  X then O
//      G  [64][136] @25600 (17408)  Q|K ; Ps = G + wave*1024 (col-swizzled)
//      Vt [64][72]  @43008 (9216)
//      biasQ u8[1350] @52224
//      Pout [192][72] @25600 (27648, aliases G+Vt+bias[0:1024), all dead)
__global__ __launch_bounds__(512, 6) void attn_kernel(
    const u16* __restrict__ xn, const u16* __restrict__ wq, const u16* __restrict__ wp,
    const float* __restrict__ qkvb, const float* __restrict__ projb,
    const u8* __restrict__ bq, u16* __restrict__ pw)
{
  __shared__ __attribute__((aligned(16))) unsigned char smem[53576];
  u16* Xs    = (u16*)smem;
  u16* G     = (u16*)(smem + 25600);
  u16* Vt    = (u16*)(smem + 43008);
  u8*  biasQ = (u8*)(smem + 52224);
  u16* Pout  = (u16*)(smem + 25600);

  const int t    = threadIdx.x;
  const int lane = t & 63;
  const int wave = t >> 6;
  const int arow = lane & 15;
  const int kgrp = lane >> 4;

  const int bid = blockIdx.x;
  const int wid = (bid & 7) * 512 + (bid >> 3);   // XCD-contiguous
  const int b   = wid >> 10;
  const int wh  = (wid >> 5) & 31;
  const int ww  = wid & 31;

  // ---- stage: contiguous bf16 window + bias table ----
  const u16* src = xn + (long)wid*12288;
  #pragma unroll
  for (int it = 0; it < 3; ++it) {
    const int id = it*512 + t;
    const int row = id/24, c8 = (id%24)*8;
    *(u16x8*)&Xs[row*200 + c8] = *(const u16x8*)(src + id*8);
  }
  for (int i = t; i < 1350; i += 512) biasQ[i] = bq[i];
  __syncthreads();

  const int hh = wave >> 2;
  const int mt = wave & 3;
  u16x4 og[3][2];

  #pragma unroll
  for (int g = 0; g < 3; ++g) {
    // QKV slice GEMM: 12 ntiles over 8 waves
    for (int nt0 = wave; nt0 < 12; nt0 += 8) {
      f32x4 acc[4] = {{0,0,0,0},{0,0,0,0},{0,0,0,0},{0,0,0,0}};
      const int col = nt0*16 + arow;
      const int mat = col >> 6;                 // 0 Q, 1 K, 2 V
      const int ch  = mat*192 + g*64 + (col & 63);
      const u16* wrow = wq + ch*192 + kgrp*8;
      #pragma unroll
      for (int ks = 0; ks < 6; ++ks) {
        u16x8 bfr = *(const u16x8*)(wrow + ks*32);
        #pragma unroll
        for (int m = 0; m < 4; ++m) {
          u16x8 af = *(const u16x8*)&Xs[(m*16+arow)*200 + ks*32 + kgrp*8];
          acc[m] = mfma16(af, bfr, acc[m]);
        }
      }
      const float addb = qkvb[ch];
      if (mat == 2) {
        const int vc = col & 63;
        #pragma unroll
        for (int m = 0; m < 4; ++m) {
          u16x4 pk;
          #pragma unroll
          for (int r = 0; r < 4; ++r) pk[r] = f2bf(acc[m][r] + addb);
          *(u16x4*)&Vt[vc*72 + m*16 + kgrp*4] = pk;
        }
      } else {
        const float mult = (mat == 0) ? 0.17677669529663687f : 1.0f;
        const int gc = mat*64 + (col & 63);
        #pragma unroll
        for (int m = 0; m < 4; ++m)
          #pragma unroll
          for (int r = 0; r < 4; ++r)
            G[(m*16 + kgrp*4 + r)*136 + gc] = f2bf((acc[m][r] + addb)*mult);
      }
    }
    __syncthreads();

    // attention: one (hh,mt) task per wave
    const int hd = g*2 + hh;
    u16x8 qf = *(const u16x8*)&G[(mt*16+arow)*136 + hh*32 + kgrp*8];
    f32x4 sv[4];
    #pragma unroll
    for (int nt = 0; nt < 4; ++nt) {
      u16x8 kf = *(const u16x8*)&G[(nt*16+arow)*136 + 64 + hh*32 + kgrp*8];
      f32x4 z = {0,0,0,0};
      sv[nt] = mfma16(qf, kf, z);
    }
    __syncthreads();   // all G(Q,K) reads done; Ps may overwrite G

    float p[4][4];
    #pragma unroll
    for (int r = 0; r < 4; ++r) {
      const int i  = mt*16 + kgrp*4 + r;
      const int iy = i >> 3, ix = i & 7;
      const int ri = ((wh==31) ? (iy<4?1:2) : 0)*3 + ((ww==31) ? (ix<4?1:2) : 0);
      #pragma unroll
      for (int nt = 0; nt < 4; ++nt) {
        const int j  = nt*16 + arow;
        const int jy = j >> 3, jx = j & 7;
        const int rj = ((wh==31) ? (jy<4?1:2) : 0)*3 + ((ww==31) ? (jx<4?1:2) : 0);
        const int bidx = ((iy-jy+7)*15 + (ix-jx+7))*6 + hd;
        float s = sv[nt][r] + (float)((int)biasQ[bidx] - 128) * 0.0078125f;
        if (ri != rj) s -= 100.0f;
        p[nt][r] = s;
      }
    }
    #pragma unroll
    for (int r = 0; r < 4; ++r) {
      float mx = fmaxf(fmaxf(p[0][r], p[1][r]), fmaxf(p[2][r], p[3][r]));
      for (int off = 1; off < 16; off <<= 1) mx = fmaxf(mx, __shfl_xor(mx, off, 64));
      float sum = 0.f;
      #pragma unroll
      for (int nt = 0; nt < 4; ++nt) { p[nt][r] = __expf(p[nt][r] - mx); sum += p[nt][r]; }
      for (int off = 1; off < 16; off <<= 1) sum += __shfl_xor(sum, off, 64);
      const float inv = 1.0f / sum;
      #pragma unroll
      for (int nt = 0; nt < 4; ++nt) p[nt][r] *= inv;
    }
    // P -> col-swizzled per-wave scratch inside dead G
    u16* myP = G + wave*1024;
    #pragma unroll
    for (int r = 0; r < 4; ++r) {
      const int i = kgrp*4 + r;
      #pragma unroll
      for (int nt = 0; nt < 4; ++nt) {
        const int j = nt*16 + arow;
        myP[i*64 + ((j + 8*i) & 63)] = f2bf(p[nt][r]);
      }
    }
    f32x4 oacc[2] = {{0,0,0,0},{0,0,0,0}};
    #pragma unroll
    for (int ks = 0; ks < 2; ++ks) {
      u16x8 pf = *(const u16x8*)&myP[arow*64 + ((ks*32 + kgrp*8 + 8*arow) & 63)];
      #pragma unroll
      for (int nt = 0; nt < 2; ++nt) {
        u16x8 vf = *(const u16x8*)&Vt[(hh*32 + nt*16 + arow)*72 + ks*32 + kgrp*8];
        oacc[nt] = mfma16(pf, vf, oacc[nt]);
      }
    }
    #pragma unroll
    for (int nt = 0; nt < 2; ++nt)
      #pragma unroll
      for (int r = 0; r < 4; ++r)
        og[g][nt][r] = f2bf(oacc[nt][r]);
    __syncthreads();   // end-g: next QKV overwrites G/Vt
  }

  // ---- O (regs) -> Xs ----
  #pragma unroll
  for (int g = 0; g < 3; ++g)
    #pragma unroll
    for (int nt = 0; nt < 2; ++nt) {
      const int colb = g*64 + hh*32 + nt*16 + arow;
      #pragma unroll
      for (int r = 0; r < 4; ++r)
        Xs[(mt*16 + kgrp*4 + r)*200 + colb] = og[g][nt][r];
    }
  __syncthreads();

  // ---- proj GEMM -> Pout [ch][tok] ----
  for (int nt0 = wave; nt0 < 12; nt0 += 8) {
    const int ch = nt0*16 + arow;
    const float pb = projb[ch];
    f32x4 acc[4];
    #pragma unroll
    for (int m = 0; m < 4; ++m) { f32x4 v = {pb,pb,pb,pb}; acc[m] = v; }
    const u16* wrow = wp + ch*192 + kgrp*8;
    #pragma unroll
    for (int ks = 0; ks < 6; ++ks) {
      u16x8 bfr = *(const u16x8*)(wrow + ks*32);
      #pragma unroll
      for (int m = 0; m < 4; ++m) {
        u16x8 af = *(const u16x8*)&Xs[(m*16+arow)*200 + ks*32 + kgrp*8];
        acc[m] = mfma16(af, bfr, acc[m]);
      }
    }
    #pragma unroll
    for (int m = 0; m < 4; ++m) {
      u16x4 pk;
      #pragma unroll
      for (int r = 0; r < 4; ++r) pk[r] = f2bf(acc[m][r]);
      *(u16x4*)&Pout[ch*72 + m*16 + kgrp*4] = pk;
    }
  }
  __syncthreads();

  // ---- epilogue: Pout -> global pw [wid][c][tok], contiguous b128 ----
  u16* dst = pw + (long)wid*12288;
  #pragma unroll
  for (int it = 0; it < 3; ++it) {
    const int id = it*512 + t;
    const int c = id >> 3, off = (id & 7)*8;
    *(u16x8*)(dst + c*64 + off) = *(const u16x8*)&Pout[c*72 + off];
  }
}

// ---- merge: out = x + proj (full-line I/O) + fused stats2 partials ----
// block = (b, gy, c-chunk32)
__global__ __launch_bounds__(256) void merge_kernel(
    const float* __restrict__ x, const u16* __restrict__ pw,
    float* __restrict__ out, float* __restrict__ st2)
{
  __shared__ u16 tile[32*264];
  const int t = threadIdx.x;
  const int bid = blockIdx.x;
  const int cc = bid % 6;
  const int gy = (bid/6) & 255;
  const int b  = bid / 1536;
  const int c0 = cc*32;
  const int gys = (gy + 252) & 255;    // gy - 4
  const int wh = gys >> 3, ay = gys & 7;

  // phase A: gather projW for this row
  {
    const int ww = t >> 3, cq = t & 7;
    const long wid = b*1024 + wh*32 + ww;
    const u16* srcw = pw + wid*12288;
    const int g1 = ww*8 + 4, g2 = (ww*8 + 8) & 255;
    #pragma unroll
    for (int j = 0; j < 4; ++j) {
      const int c = cq*4 + j;
      u16x8 v = *(const u16x8*)(srcw + (c0+c)*64 + ay*8);
      const int sw = (c & 7) << 2;
      u16x4 lo = {v[0],v[1],v[2],v[3]}, hi = {v[4],v[5],v[6],v[7]};
      *(u16x4*)&tile[c*264 + (g1 ^ sw)] = lo;
      *(u16x4*)&tile[c*264 + (g2 ^ sw)] = hi;
    }
  }
  __syncthreads();

  // phase B: out = x + proj, stats partials
  const int cl = t >> 3, seg = t & 7;
  const int c = c0 + cl;
  const long base = (((long)(b*192 + c)) << 16) + gy*256 + seg*32;
  const float* xr = x + base;
  float* orow = out + base;
  const int sw = (cl & 7) << 2;
  float s = 0.f, ss = 0.f;
  #pragma unroll
  for (int q4 = 0; q4 < 32; q4 += 4) {
    const int px = seg*32 + q4;
    u16x4 pv = *(const u16x4*)&tile[cl*264 + (px ^ sw)];
    float4 xv = *(const float4*)(xr + q4);
    float4 o;
    o.x = xv.x + bf2f(pv[0]);
    o.y = xv.y + bf2f(pv[1]);
    o.z = xv.z + bf2f(pv[2]);
    o.w = xv.w + bf2f(pv[3]);
    *(float4*)(orow + q4) = o;
    s  += o.x + o.y + o.z + o.w;
    ss += o.x*o.x + o.y*o.y + o.z*o.z + o.w*o.w;
  }
  for (int off = 1; off < 8; off <<= 1) {
    s  += __shfl_xor(s,  off, 64);
    ss += __shfl_xor(ss, off, 64);
  }
  if (seg == 0) {
    atomicAdd(&st2[(b*192+c)*2],     s);
    atomicAdd(&st2[(b*192+c)*2 + 1], ss);
  }
}

// ---- FiLM + residual, in place ----
__global__ void film_kernel(float* __restrict__ io, const float* __restrict__ st2,
                            const float* __restrict__ gb) {
  const long total = (long)BATCH*CH*PLANE/4;
  for (long i = (long)blockIdx.x*blockDim.x + threadIdx.x; i < total;
       i += (long)gridDim.x*blockDim.x) {
    const int plane = (int)(i >> 14);
    const int bb = plane / CH, c = plane - bb*CH;
    const float sm = st2[plane*2], ssum = st2[plane*2+1];
    const float mean = sm * (1.f/PLANE);
    const float var  = ssum * (1.f/PLANE) - mean*mean;
    const float rstd = rsqrtf(var + 1e-5f);
    const float g  = gb[bb*384 + c];
    const float be = gb[bb*384 + 192 + c];
    float4 v = ((const float4*)io)[i];
    float4 o;
    o.x = v.x + (v.x - mean)*rstd*g + be;
    o.y = v.y + (v.y - mean)*rstd*g + be;
    o.z = v.z + (v.z - mean)*rstd*g + be;
    o.w = v.w + (v.w - mean)*rstd*g + be;
    ((float4*)io)[i] = o;
  }
}

extern "C" void kernel_launch(void* const* d_in, const int* in_sizes, int n_in,
                              void* d_out, int out_size, void* d_ws, size_t ws_size,
                              hipStream_t stream) {
  const float* x      = (const float*)d_in[0];
  const float* cond   = (const float*)d_in[1];
  const float* qkv_w  = (const float*)d_in[2];
  const float* qkv_b  = (const float*)d_in[3];
  const float* proj_w = (const float*)d_in[4];
  const float* proj_b = (const float*)d_in[5];
  const float* relb   = (const float*)d_in[6];
  const float* film_w = (const float*)d_in[7];
  const float* film_b = (const float*)d_in[8];
  float* out = (float*)d_out;

  char* ws = (char*)d_ws;
  float* stats1 = (float*)ws;                    // 768*2 f32
  float* st2    = (float*)(ws + 6144);           // 768*2 f32 (sum, sumsq)
  float* gb     = (float*)(ws + 12288);          // 4*384 f32
  u16*   wq     = (u16*)(ws + 18432);            // 576*192 bf16
  u16*   wp     = (u16*)(ws + 18432 + 221184);   // 192*192 bf16
  u8*    bqq    = (u8*)(ws + 313344);            // 1350 u8
  u16*   xnb    = (u16*)(ws + 314880);           // 4096*64*192 bf16 (Xn, then projW)

  zero_kernel<<<6, 256, 0, stream>>>(st2);
  stats_kernel<<<768, 256, 0, stream>>>(x, stats1);
  cvt_kernel<<<432, 256, 0, stream>>>(qkv_w, proj_w, relb, wq, wp, bqq);
  film_prep<<<6, 256, 0, stream>>>(cond, film_w, film_b, gb);
  prep_kernel<<<768, 256, 0, stream>>>(x, stats1, xnb);
  attn_kernel<<<4096, 512, 0, stream>>>(xnb, wq, wp, qkv_b, proj_b, bqq, xnb);
  merge_kernel<<<6144, 256, 0, stream>>>(x, xnb, out, st2);
  film_kernel<<<2048, 256, 0, stream>>>(out, st2, gb);
}

// Round 4
// 699.098 us; speedup vs baseline: 1.0741x; 1.0741x over previous
//
#include <hip/hip_runtime.h>

#define BATCH 4
#define CH    192
#define PLANE 65536

typedef unsigned short u16;
typedef __bf16 bf16x8_t __attribute__((ext_vector_type(8)));
typedef unsigned short u16x8 __attribute__((ext_vector_type(8)));
typedef unsigned short u16x4 __attribute__((ext_vector_type(4)));
typedef float f32x4 __attribute__((ext_vector_type(4)));

__device__ __forceinline__ u16 f2bf(float f) {
  __bf16 h = (__bf16)f;                       // hardware RNE cvt
  return __builtin_bit_cast(u16, h);
}
__device__ __forceinline__ float bf2f(u16 h) {
  unsigned u = ((unsigned)h) << 16;
  return __builtin_bit_cast(float, u);
}
__device__ __forceinline__ f32x4 mfma16(u16x8 a, u16x8 b, f32x4 c) {
  return __builtin_amdgcn_mfma_f32_16x16x32_bf16(
      __builtin_bit_cast(bf16x8_t, a), __builtin_bit_cast(bf16x8_t, b), c, 0, 0, 0);
}
// granule swizzle for Xs (matches stage-write / A-frag-read / O-write / proj-read)
__device__ __forceinline__ int swz(int row, int gran) {
  return gran ^ (row & 7) ^ ((row >> 3) & 7);
}

// ---- per-(b,c) instance-norm stats for x ----
__global__ void stats_kernel(const float* __restrict__ in, float* __restrict__ st) {
  const int plane = blockIdx.x;
  const float4* p = (const float4*)(in + (long)plane * PLANE);
  float s = 0.f, ss = 0.f;
  for (int i = threadIdx.x; i < PLANE/4; i += 256) {
    float4 v = p[i];
    s  += v.x + v.y + v.z + v.w;
    ss += v.x*v.x + v.y*v.y + v.z*v.z + v.w*v.w;
  }
  for (int off = 1; off < 64; off <<= 1) {
    s  += __shfl_xor(s,  off, 64);
    ss += __shfl_xor(ss, off, 64);
  }
  __shared__ float aux[4][2];
  const int w = threadIdx.x >> 6;
  if ((threadIdx.x & 63) == 0) { aux[w][0] = s; aux[w][1] = ss; }
  __syncthreads();
  if (threadIdx.x == 0) {
    float S  = aux[0][0]+aux[1][0]+aux[2][0]+aux[3][0];
    float SS = aux[0][1]+aux[1][1]+aux[2][1]+aux[3][1];
    float mean = S * (1.f/PLANE);
    float var  = SS * (1.f/PLANE) - mean*mean;
    st[plane*2]   = mean;
    st[plane*2+1] = rsqrtf(var + 1e-5f);
  }
}

// ---- weights -> bf16, rel_bias -> expanded bf16 [head][64][64] ----
__global__ void cvt_kernel(const float* __restrict__ a, const float* __restrict__ b,
                           const float* __restrict__ rb,
                           u16* __restrict__ wa, u16* __restrict__ wb,
                           u16* __restrict__ bias6) {
  const int i = blockIdx.x*256 + threadIdx.x;
  if (i < 576*192) wa[i] = f2bf(a[i]);
  if (i < 192*192) wb[i] = f2bf(b[i]);
  if (i < 6*4096) {
    const int hd = i >> 12;
    const int ii = (i >> 6) & 63, jj = i & 63;
    const int iy = ii >> 3, ix = ii & 7, jy = jj >> 3, jx = jj & 7;
    const int bidx = (iy - jy + 7)*15 + (ix - jx + 7);
    bias6[i] = f2bf(rb[bidx*6 + hd]);
  }
}

// ---- gamma/beta + zero st2 ----
__global__ void film_prep(const float* __restrict__ cond, const float* __restrict__ fw,
                          const float* __restrict__ fb, float* __restrict__ gb,
                          float* __restrict__ st2) {
  const int i = blockIdx.x*256 + threadIdx.x;
  if (i >= BATCH*384) return;
  st2[i] = 0.f;
  const int bb = i / 384, oc = i - bb*384;
  const float* cw = fw + oc*128;
  const float* cv = cond + bb*128;
  float s = fb[oc];
  for (int k = 0; k < 128; ++k) s += cv[k]*cw[k];
  gb[i] = s;
}

// ---- fused: normalize + window attention + proj + residual; v=x+proj -> pw ----
// LDS: Xs [64][200] @0 (25600)  normalized X, later O (granule-swizzled)
//      G  [64][136] @25600 (17408)  Q|K ; Ps = G + wave*1024 (col-rotated)
//      Vt [64][72]  @43008 (9216)
//      Pout [192][72] @25600 (27648, aliases G+Vt after attention)
__global__ __launch_bounds__(512, 6) void attn_kernel(
    const float* __restrict__ x, const float* __restrict__ st,
    const u16* __restrict__ wq, const u16* __restrict__ wp,
    const float* __restrict__ qkvb, const float* __restrict__ projb,
    const u16* __restrict__ bias6, u16* __restrict__ pw, float* __restrict__ st2)
{
  __shared__ __attribute__((aligned(16))) unsigned char smem[53248];
  u16* Xs   = (u16*)smem;
  u16* G    = (u16*)(smem + 25600);
  u16* Vt   = (u16*)(smem + 43008);
  u16* Pout = (u16*)(smem + 25600);

  const int t    = threadIdx.x;
  const int lane = t & 63;
  const int wave = t >> 6;
  const int arow = lane & 15;
  const int kgrp = lane >> 4;

  const int bid = blockIdx.x;
  const int wid = (bid & 7) * 512 + (bid >> 3);   // XCD-contiguous
  const int b   = wid >> 10;
  const int wh  = (wid >> 5) & 31;
  const int ww  = wid & 31;

  // ---- stage: float4 x loads, normalize -> Xs (swizzled); raw x in fp32 regs ----
  const int cbase = t >> 4;            // channel-within-32 chunk
  const int ay    = (t >> 1) & 7;
  const int half  = t & 1;
  const int gy    = (wh*8 + ay + 4) & 255;
  const int gx0   = (ww*8 + half*4 + 4) & 255;
  const long spo  = (long)gy*256 + gx0;
  const int tok0  = ay*8 + half*4;
  const float* xb = x + (long)b*CH*PLANE;

  float4 xr[6];
  #pragma unroll
  for (int it = 0; it < 6; ++it) {
    const int c = it*32 + cbase;
    const float m = st[(b*192+c)*2], r = st[(b*192+c)*2+1];
    float4 v = *(const float4*)(xb + (long)c*PLANE + spo);
    xr[it] = v;
    float va[4] = {v.x, v.y, v.z, v.w};
    #pragma unroll
    for (int j = 0; j < 4; ++j) {
      const int row = tok0 + j;
      Xs[row*200 + (swz(row, c>>3)<<3) + (c&7)] = f2bf((va[j] - m) * r);
    }
  }
  __syncthreads();

  const int hh = wave >> 2;
  const int mt = wave & 3;
  const bool boundary = (wh == 31) || (ww == 31);
  u16x4 og[3][2];

  #pragma unroll
  for (int g = 0; g < 3; ++g) {
    // QKV slice GEMM: 12 ntiles over 8 waves
    for (int nt0 = wave; nt0 < 12; nt0 += 8) {
      f32x4 acc[4] = {{0,0,0,0},{0,0,0,0},{0,0,0,0},{0,0,0,0}};
      const int col = nt0*16 + arow;
      const int mat = col >> 6;                 // 0 Q, 1 K, 2 V
      const int ch  = mat*192 + g*64 + (col & 63);
      const u16* wrow = wq + ch*192 + kgrp*8;
      __builtin_amdgcn_s_setprio(1);
      #pragma unroll
      for (int ks = 0; ks < 6; ++ks) {
        u16x8 bfr = *(const u16x8*)(wrow + ks*32);
        #pragma unroll
        for (int m = 0; m < 4; ++m) {
          const int row = m*16 + arow;
          u16x8 af = *(const u16x8*)&Xs[row*200 + (swz(row, ks*4 + kgrp)<<3)];
          acc[m] = mfma16(af, bfr, acc[m]);
        }
      }
      __builtin_amdgcn_s_setprio(0);
      const float addb = qkvb[ch];
      if (mat == 2) {
        const int vc = col & 63;
        #pragma unroll
        for (int m = 0; m < 4; ++m) {
          u16x4 pk;
          #pragma unroll
          for (int r = 0; r < 4; ++r) pk[r] = f2bf(acc[m][r] + addb);
          *(u16x4*)&Vt[vc*72 + m*16 + kgrp*4] = pk;
        }
      } else {
        const float mult = (mat == 0) ? 0.17677669529663687f : 1.0f;
        const int gc = mat*64 + (col & 63);
        #pragma unroll
        for (int m = 0; m < 4; ++m)
          #pragma unroll
          for (int r = 0; r < 4; ++r)
            G[(m*16 + kgrp*4 + r)*136 + gc] = f2bf((acc[m][r] + addb)*mult);
      }
    }
    __syncthreads();

    // attention: one (hh,mt) task per wave
    const int hd = g*2 + hh;
    u16x8 qf = *(const u16x8*)&G[(mt*16+arow)*136 + hh*32 + kgrp*8];
    f32x4 sv[4];
    #pragma unroll
    for (int nt = 0; nt < 4; ++nt) {
      u16x8 kf = *(const u16x8*)&G[(nt*16+arow)*136 + 64 + hh*32 + kgrp*8];
      f32x4 z = {0,0,0,0};
      sv[nt] = mfma16(qf, kf, z);
    }
    __syncthreads();   // G(Q,K) reads done; Ps may overwrite G

    // bias (global bf16 table, L1-hot) + optional boundary mask
    const u16* Bh = bias6 + hd*4096;
    float p[4][4];
    if (!boundary) {
      #pragma unroll
      for (int r = 0; r < 4; ++r) {
        const int i = mt*16 + kgrp*4 + r;
        #pragma unroll
        for (int nt = 0; nt < 4; ++nt) {
          const int j = nt*16 + arow;
          p[nt][r] = sv[nt][r] + bf2f(Bh[i*64 + j]);
        }
      }
    } else {
      #pragma unroll
      for (int r = 0; r < 4; ++r) {
        const int i  = mt*16 + kgrp*4 + r;
        const int iy = i >> 3, ix = i & 7;
        const int ri = ((wh==31) ? (iy<4?1:2) : 0)*3 + ((ww==31) ? (ix<4?1:2) : 0);
        #pragma unroll
        for (int nt = 0; nt < 4; ++nt) {
          const int j  = nt*16 + arow;
          const int jy = j >> 3, jx = j & 7;
          const int rj = ((wh==31) ? (jy<4?1:2) : 0)*3 + ((ww==31) ? (jx<4?1:2) : 0);
          float s = sv[nt][r] + bf2f(Bh[i*64 + j]);
          if (ri != rj) s -= 100.0f;
          p[nt][r] = s;
        }
      }
    }
    #pragma unroll
    for (int r = 0; r < 4; ++r) {
      float mx = fmaxf(fmaxf(p[0][r], p[1][r]), fmaxf(p[2][r], p[3][r]));
      for (int off = 1; off < 16; off <<= 1) mx = fmaxf(mx, __shfl_xor(mx, off, 64));
      float sum = 0.f;
      #pragma unroll
      for (int nt = 0; nt < 4; ++nt) { p[nt][r] = __expf(p[nt][r] - mx); sum += p[nt][r]; }
      for (int off = 1; off < 16; off <<= 1) sum += __shfl_xor(sum, off, 64);
      const float inv = 1.0f / sum;
      #pragma unroll
      for (int nt = 0; nt < 4; ++nt) p[nt][r] *= inv;
    }
    // P -> col-rotated per-wave scratch in dead G
    u16* myP = G + wave*1024;
    #pragma unroll
    for (int r = 0; r < 4; ++r) {
      const int i = kgrp*4 + r;
      #pragma unroll
      for (int nt = 0; nt < 4; ++nt) {
        const int j = nt*16 + arow;
        myP[i*64 + ((j + 8*i) & 63)] = f2bf(p[nt][r]);
      }
    }
    f32x4 oacc[2] = {{0,0,0,0},{0,0,0,0}};
    __builtin_amdgcn_s_setprio(1);
    #pragma unroll
    for (int ks = 0; ks < 2; ++ks) {
      u16x8 pf = *(const u16x8*)&myP[arow*64 + ((ks*32 + kgrp*8 + 8*arow) & 63)];
      #pragma unroll
      for (int nt = 0; nt < 2; ++nt) {
        u16x8 vf = *(const u16x8*)&Vt[(hh*32 + nt*16 + arow)*72 + ks*32 + kgrp*8];
        oacc[nt] = mfma16(pf, vf, oacc[nt]);
      }
    }
    __builtin_amdgcn_s_setprio(0);
    #pragma unroll
    for (int nt = 0; nt < 2; ++nt)
      #pragma unroll
      for (int r = 0; r < 4; ++r)
        og[g][nt][r] = f2bf(oacc[nt][r]);
    __syncthreads();   // end-g: next QKV overwrites G/Vt
  }

  // ---- O (regs) -> Xs (swizzled) ----
  #pragma unroll
  for (int g = 0; g < 3; ++g)
    #pragma unroll
    for (int nt = 0; nt < 2; ++nt) {
      const int colb = g*64 + hh*32 + nt*16 + arow;
      #pragma unroll
      for (int r = 0; r < 4; ++r) {
        const int row = mt*16 + kgrp*4 + r;
        Xs[row*200 + (swz(row, colb>>3)<<3) + (colb&7)] = og[g][nt][r];
      }
    }
  __syncthreads();

  // ---- proj GEMM -> Pout [ch][tok] ----
  for (int nt0 = wave; nt0 < 12; nt0 += 8) {
    const int ch = nt0*16 + arow;
    const float pb = projb[ch];
    f32x4 acc[4];
    #pragma unroll
    for (int m = 0; m < 4; ++m) { f32x4 v = {pb,pb,pb,pb}; acc[m] = v; }
    const u16* wrow = wp + ch*192 + kgrp*8;
    __builtin_amdgcn_s_setprio(1);
    #pragma unroll
    for (int ks = 0; ks < 6; ++ks) {
      u16x8 bfr = *(const u16x8*)(wrow + ks*32);
      #pragma unroll
      for (int m = 0; m < 4; ++m) {
        const int row = m*16 + arow;
        u16x8 af = *(const u16x8*)&Xs[row*200 + (swz(row, ks*4 + kgrp)<<3)];
        acc[m] = mfma16(af, bfr, acc[m]);
      }
    }
    __builtin_amdgcn_s_setprio(0);
    #pragma unroll
    for (int m = 0; m < 4; ++m) {
      u16x4 pk;
      #pragma unroll
      for (int r = 0; r < 4; ++r) pk[r] = f2bf(acc[m][r]);
      *(u16x4*)&Pout[ch*72 + m*16 + kgrp*4] = pk;
    }
  }
  __syncthreads();

  // ---- epilogue: v = x + proj; bf16 v -> pw [wid][c][64tok]; stats2 partials ----
  u16* dstw = pw + (long)wid*12288;
  #pragma unroll
  for (int it = 0; it < 6; ++it) {
    const int c = it*32 + cbase;
    u16x4 pv = *(const u16x4*)&Pout[c*72 + tok0];
    float v0 = xr[it].x + bf2f(pv[0]);
    float v1 = xr[it].y + bf2f(pv[1]);
    float v2 = xr[it].z + bf2f(pv[2]);
    float v3 = xr[it].w + bf2f(pv[3]);
    u16x4 vb;
    vb[0] = f2bf(v0); vb[1] = f2bf(v1); vb[2] = f2bf(v2); vb[3] = f2bf(v3);
    *(u16x4*)(dstw + c*64 + tok0) = vb;
    float s  = v0 + v1 + v2 + v3;
    float ss = v0*v0 + v1*v1 + v2*v2 + v3*v3;
    for (int off = 1; off < 16; off <<= 1) {
      s  += __shfl_xor(s,  off, 64);
      ss += __shfl_xor(ss, off, 64);
    }
    if ((lane & 15) == 0) {
      atomicAdd(&st2[(b*192+c)*2],     s);
      atomicAdd(&st2[(b*192+c)*2 + 1], ss);
    }
  }
}

// ---- final: out = v + FiLM(norm2(v)); gathers window-major v, full-line writes ----
__global__ __launch_bounds__(256) void final_kernel(
    const u16* __restrict__ pw, const float* __restrict__ st2,
    const float* __restrict__ gb, float* __restrict__ out)
{
  __shared__ u16 tile[32*264];
  const int t = threadIdx.x;
  const int bid = blockIdx.x;
  const int lin = (bid & 7)*768 + (bid >> 3);      // XCD-contiguous row bands
  const int cc = lin % 6;
  const int rowid = lin / 6;
  const int gy = rowid & 255;
  const int b  = rowid >> 8;
  const int c0 = cc*32;
  const int gys = (gy + 252) & 255;                // gy - 4
  const int wh = gys >> 3, ay = gys & 7;

  // phase A: gather v for this output row
  {
    const int ww = t >> 3, cq = t & 7;
    const long wid = b*1024 + wh*32 + ww;
    const u16* srcw = pw + wid*12288;
    const int g1 = ww*8 + 4, g2 = (ww*8 + 8) & 255;
    #pragma unroll
    for (int j = 0; j < 4; ++j) {
      const int c = cq*4 + j;
      u16x8 v = *(const u16x8*)(srcw + (c0+c)*64 + ay*8);
      const int sw = (c & 7) << 2;
      u16x4 lo = {v[0],v[1],v[2],v[3]}, hi = {v[4],v[5],v[6],v[7]};
      *(u16x4*)&tile[c*264 + (g1 ^ sw)] = lo;
      *(u16x4*)&tile[c*264 + (g2 ^ sw)] = hi;
    }
  }
  __syncthreads();

  // phase B: out = v + (v-mean)*rstd*gamma + beta, full-line fp32 stores
  const int cl = t >> 3, seg = t & 7;
  const int c = c0 + cl;
  const float sm   = st2[(b*192+c)*2];
  const float ssum = st2[(b*192+c)*2 + 1];
  const float mean = sm * (1.f/PLANE);
  const float var  = ssum * (1.f/PLANE) - mean*mean;
  const float rstd = rsqrtf(var + 1e-5f);
  const float gmm  = gb[b*384 + c];
  const float be   = gb[b*384 + 192 + c];
  const long base = (((long)(b*192 + c)) << 16) + gy*256 + seg*32;
  float* orow = out + base;
  const int sw = (cl & 7) << 2;
  #pragma unroll
  for (int q4 = 0; q4 < 32; q4 += 4) {
    const int px = seg*32 + q4;
    u16x4 pv = *(const u16x4*)&tile[cl*264 + (px ^ sw)];
    float4 o;
    float v0 = bf2f(pv[0]), v1 = bf2f(pv[1]), v2 = bf2f(pv[2]), v3 = bf2f(pv[3]);
    o.x = v0 + (v0 - mean)*rstd*gmm + be;
    o.y = v1 + (v1 - mean)*rstd*gmm + be;
    o.z = v2 + (v2 - mean)*rstd*gmm + be;
    o.w = v3 + (v3 - mean)*rstd*gmm + be;
    *(float4*)(orow + q4) = o;
  }
}

extern "C" void kernel_launch(void* const* d_in, const int* in_sizes, int n_in,
                              void* d_out, int out_size, void* d_ws, size_t ws_size,
                              hipStream_t stream) {
  const float* x      = (const float*)d_in[0];
  const float* cond   = (const float*)d_in[1];
  const float* qkv_w  = (const float*)d_in[2];
  const float* qkv_b  = (const float*)d_in[3];
  const float* proj_w = (const float*)d_in[4];
  const float* proj_b = (const float*)d_in[5];
  const float* relb   = (const float*)d_in[6];
  const float* film_w = (const float*)d_in[7];
  const float* film_b = (const float*)d_in[8];
  float* out = (float*)d_out;

  char* ws = (char*)d_ws;
  float* stats1 = (float*)ws;                    // 768*2 f32
  float* st2    = (float*)(ws + 6144);           // 768*2 f32 (sum, sumsq)
  float* gb     = (float*)(ws + 12288);          // 4*384 f32
  u16*   wq     = (u16*)(ws + 18432);            // 576*192 bf16
  u16*   wp     = (u16*)(ws + 239616);           // 192*192 bf16
  u16*   bias6  = (u16*)(ws + 313344);           // 6*64*64 bf16
  u16*   pw     = (u16*)(ws + 362496);           // 4096*192*64 bf16 (v)

  stats_kernel<<<768, 256, 0, stream>>>(x, stats1);
  cvt_kernel<<<432, 256, 0, stream>>>(qkv_w, proj_w, relb, wq, wp, bias6);
  film_prep<<<6, 256, 0, stream>>>(cond, film_w, film_b, gb, st2);
  attn_kernel<<<4096, 512, 0, stream>>>(x, stats1, wq, wp, qkv_b, proj_b, bias6, pw, st2);
  final_kernel<<<6144, 256, 0, stream>>>(pw, st2, gb, out);
}

// Round 5
// 581.695 us; speedup vs baseline: 1.2909x; 1.2018x over previous
//
#include <hip/hip_runtime.h>

#define BATCH 4
#define CH    192
#define PLANE 65536

typedef unsigned short u16;
typedef __bf16 bf16x8_t __attribute__((ext_vector_type(8)));
typedef unsigned short u16x8 __attribute__((ext_vector_type(8)));
typedef unsigned short u16x4 __attribute__((ext_vector_type(4)));
typedef float f32x4 __attribute__((ext_vector_type(4)));

__device__ __forceinline__ u16 f2bf(float f) {
  __bf16 h = (__bf16)f;                       // hardware RNE cvt
  return __builtin_bit_cast(u16, h);
}
__device__ __forceinline__ float bf2f(u16 h) {
  unsigned u = ((unsigned)h) << 16;
  return __builtin_bit_cast(float, u);
}
__device__ __forceinline__ f32x4 mfma16(u16x8 a, u16x8 b, f32x4 c) {
  return __builtin_amdgcn_mfma_f32_16x16x32_bf16(
      __builtin_bit_cast(bf16x8_t, a), __builtin_bit_cast(bf16x8_t, b), c, 0, 0, 0);
}
// granule swizzle for Xs (matches stage-write / A-frag-read / O-write / proj-read)
__device__ __forceinline__ int swz(int row, int gran) {
  return gran ^ (row & 7) ^ ((row >> 3) & 7);
}

// ---- per-(b,c) instance-norm stats for x ----
__global__ void stats_kernel(const float* __restrict__ in, float* __restrict__ st) {
  const int plane = blockIdx.x;
  const float4* p = (const float4*)(in + (long)plane * PLANE);
  float s = 0.f, ss = 0.f;
  for (int i = threadIdx.x; i < PLANE/4; i += 256) {
    float4 v = p[i];
    s  += v.x + v.y + v.z + v.w;
    ss += v.x*v.x + v.y*v.y + v.z*v.z + v.w*v.w;
  }
  for (int off = 1; off < 64; off <<= 1) {
    s  += __shfl_xor(s,  off, 64);
    ss += __shfl_xor(ss, off, 64);
  }
  __shared__ float aux[4][2];
  const int w = threadIdx.x >> 6;
  if ((threadIdx.x & 63) == 0) { aux[w][0] = s; aux[w][1] = ss; }
  __syncthreads();
  if (threadIdx.x == 0) {
    float S  = aux[0][0]+aux[1][0]+aux[2][0]+aux[3][0];
    float SS = aux[0][1]+aux[1][1]+aux[2][1]+aux[3][1];
    float mean = S * (1.f/PLANE);
    float var  = SS * (1.f/PLANE) - mean*mean;
    st[plane*2]   = mean;
    st[plane*2+1] = rsqrtf(var + 1e-5f);
  }
}

// ---- weights -> bf16, rel_bias -> expanded bf16 [head][64][64] ----
__global__ void cvt_kernel(const float* __restrict__ a, const float* __restrict__ b,
                           const float* __restrict__ rb,
                           u16* __restrict__ wa, u16* __restrict__ wb,
                           u16* __restrict__ bias6) {
  const int i = blockIdx.x*256 + threadIdx.x;
  if (i < 576*192) wa[i] = f2bf(a[i]);
  if (i < 192*192) wb[i] = f2bf(b[i]);
  if (i < 6*4096) {
    const int hd = i >> 12;
    const int ii = (i >> 6) & 63, jj = i & 63;
    const int iy = ii >> 3, ix = ii & 7, jy = jj >> 3, jx = jj & 7;
    const int bidx = (iy - jy + 7)*15 + (ix - jx + 7);
    bias6[i] = f2bf(rb[bidx*6 + hd]);
  }
}

// ---- gamma/beta + zero st2 ----
__global__ void film_prep(const float* __restrict__ cond, const float* __restrict__ fw,
                          const float* __restrict__ fb, float* __restrict__ gb,
                          float* __restrict__ st2) {
  const int i = blockIdx.x*256 + threadIdx.x;
  if (i >= BATCH*384) return;
  st2[i] = 0.f;
  const int bb = i / 384, oc = i - bb*384;
  const float* cw = fw + oc*128;
  const float* cv = cond + bb*128;
  float s = fb[oc];
  for (int k = 0; k < 128; ++k) s += cv[k]*cw[k];
  gb[i] = s;
}

// ---- fused: normalize + window attention + proj + residual; v=x+proj -> pw ----
// LDS: Xs [64][200] @0 (25600)  normalized X, later O (granule-swizzled)
//      G  [64][136] @25600 (17408)  Q|K ; Ps = G + wave*1024 (col-rotated)
//      Vt [64][72]  @43008 (9216)
//      Pout [192][72] @25600 (27648, aliases G+Vt after attention)
__global__ __launch_bounds__(512, 4) void attn_kernel(
    const float* __restrict__ x, const float* __restrict__ st,
    const u16* __restrict__ wq, const u16* __restrict__ wp,
    const float* __restrict__ qkvb, const float* __restrict__ projb,
    const u16* __restrict__ bias6, u16* __restrict__ pw, float* __restrict__ st2)
{
  __shared__ __attribute__((aligned(16))) unsigned char smem[53248];
  u16* Xs   = (u16*)smem;
  u16* G    = (u16*)(smem + 25600);
  u16* Vt   = (u16*)(smem + 43008);
  u16* Pout = (u16*)(smem + 25600);

  const int t    = threadIdx.x;
  const int lane = t & 63;
  const int wave = t >> 6;
  const int arow = lane & 15;
  const int kgrp = lane >> 4;

  const int bid = blockIdx.x;
  const int wid = (bid & 7) * 512 + (bid >> 3);   // XCD-contiguous
  const int b   = wid >> 10;
  const int wh  = (wid >> 5) & 31;
  const int ww  = wid & 31;

  // ---- stage: float4 x loads, normalize -> Xs (swizzled); raw x in bf16 regs ----
  const int cbase = t >> 4;            // channel-within-32 chunk
  const int ay    = (t >> 1) & 7;
  const int half  = t & 1;
  const int gy    = (wh*8 + ay + 4) & 255;
  const int gx0   = (ww*8 + half*4 + 4) & 255;
  const long spo  = (long)gy*256 + gx0;
  const int tok0  = ay*8 + half*4;
  const float* xb = x + (long)b*CH*PLANE;

  u16x4 xr[6];
  #pragma unroll
  for (int it = 0; it < 6; ++it) {
    const int c = it*32 + cbase;
    const float m = st[(b*192+c)*2], r = st[(b*192+c)*2+1];
    float4 v = *(const float4*)(xb + (long)c*PLANE + spo);
    float va[4] = {v.x, v.y, v.z, v.w};
    #pragma unroll
    for (int j = 0; j < 4; ++j) {
      const int row = tok0 + j;
      xr[it][j] = f2bf(va[j]);
      Xs[row*200 + (swz(row, c>>3)<<3) + (c&7)] = f2bf((va[j] - m) * r);
    }
  }
  __syncthreads();

  const int hh = wave >> 2;
  const int mt = wave & 3;
  const bool boundary = (wh == 31) || (ww == 31);
  u16x4 og[3][2];

  #pragma unroll
  for (int g = 0; g < 3; ++g) {
    // QKV slice GEMM: 12 ntiles over 8 waves
    for (int nt0 = wave; nt0 < 12; nt0 += 8) {
      f32x4 acc[4] = {{0,0,0,0},{0,0,0,0},{0,0,0,0},{0,0,0,0}};
      const int col = nt0*16 + arow;
      const int mat = col >> 6;                 // 0 Q, 1 K, 2 V
      const int ch  = mat*192 + g*64 + (col & 63);
      const u16* wrow = wq + ch*192 + kgrp*8;
      __builtin_amdgcn_s_setprio(1);
      #pragma unroll
      for (int ks = 0; ks < 6; ++ks) {
        u16x8 bfr = *(const u16x8*)(wrow + ks*32);
        #pragma unroll
        for (int m = 0; m < 4; ++m) {
          const int row = m*16 + arow;
          u16x8 af = *(const u16x8*)&Xs[row*200 + (swz(row, ks*4 + kgrp)<<3)];
          acc[m] = mfma16(af, bfr, acc[m]);
        }
      }
      __builtin_amdgcn_s_setprio(0);
      const float addb = qkvb[ch];
      if (mat == 2) {
        const int vc = col & 63;
        #pragma unroll
        for (int m = 0; m < 4; ++m) {
          u16x4 pk;
          #pragma unroll
          for (int r = 0; r < 4; ++r) pk[r] = f2bf(acc[m][r] + addb);
          *(u16x4*)&Vt[vc*72 + m*16 + kgrp*4] = pk;
        }
      } else {
        const float mult = (mat == 0) ? 0.17677669529663687f : 1.0f;
        const int gc = mat*64 + (col & 63);
        #pragma unroll
        for (int m = 0; m < 4; ++m)
          #pragma unroll
          for (int r = 0; r < 4; ++r)
            G[(m*16 + kgrp*4 + r)*136 + gc] = f2bf((acc[m][r] + addb)*mult);
      }
    }
    __syncthreads();

    // attention: one (hh,mt) task per wave
    const int hd = g*2 + hh;
    u16x8 qf = *(const u16x8*)&G[(mt*16+arow)*136 + hh*32 + kgrp*8];
    f32x4 sv[4];
    #pragma unroll
    for (int nt = 0; nt < 4; ++nt) {
      u16x8 kf = *(const u16x8*)&G[(nt*16+arow)*136 + 64 + hh*32 + kgrp*8];
      f32x4 z = {0,0,0,0};
      sv[nt] = mfma16(qf, kf, z);
    }
    __syncthreads();   // G(Q,K) reads done; Ps may overwrite G

    // bias (global bf16 table, L1-hot) + optional boundary mask
    const u16* Bh = bias6 + hd*4096;
    float p[4][4];
    if (!boundary) {
      #pragma unroll
      for (int r = 0; r < 4; ++r) {
        const int i = mt*16 + kgrp*4 + r;
        #pragma unroll
        for (int nt = 0; nt < 4; ++nt) {
          const int j = nt*16 + arow;
          p[nt][r] = sv[nt][r] + bf2f(Bh[i*64 + j]);
        }
      }
    } else {
      #pragma unroll
      for (int r = 0; r < 4; ++r) {
        const int i  = mt*16 + kgrp*4 + r;
        const int iy = i >> 3, ix = i & 7;
        const int ri = ((wh==31) ? (iy<4?1:2) : 0)*3 + ((ww==31) ? (ix<4?1:2) : 0);
        #pragma unroll
        for (int nt = 0; nt < 4; ++nt) {
          const int j  = nt*16 + arow;
          const int jy = j >> 3, jx = j & 7;
          const int rj = ((wh==31) ? (jy<4?1:2) : 0)*3 + ((ww==31) ? (jx<4?1:2) : 0);
          float s = sv[nt][r] + bf2f(Bh[i*64 + j]);
          if (ri != rj) s -= 100.0f;
          p[nt][r] = s;
        }
      }
    }
    #pragma unroll
    for (int r = 0; r < 4; ++r) {
      float mx = fmaxf(fmaxf(p[0][r], p[1][r]), fmaxf(p[2][r], p[3][r]));
      for (int off = 1; off < 16; off <<= 1) mx = fmaxf(mx, __shfl_xor(mx, off, 64));
      float sum = 0.f;
      #pragma unroll
      for (int nt = 0; nt < 4; ++nt) { p[nt][r] = __expf(p[nt][r] - mx); sum += p[nt][r]; }
      for (int off = 1; off < 16; off <<= 1) sum += __shfl_xor(sum, off, 64);
      const float inv = 1.0f / sum;
      #pragma unroll
      for (int nt = 0; nt < 4; ++nt) p[nt][r] *= inv;
    }
    // P -> col-rotated per-wave scratch in dead G
    u16* myP = G + wave*1024;
    #pragma unroll
    for (int r = 0; r < 4; ++r) {
      const int i = kgrp*4 + r;
      #pragma unroll
      for (int nt = 0; nt < 4; ++nt) {
        const int j = nt*16 + arow;
        myP[i*64 + ((j + 8*i) & 63)] = f2bf(p[nt][r]);
      }
    }
    f32x4 oacc[2] = {{0,0,0,0},{0,0,0,0}};
    __builtin_amdgcn_s_setprio(1);
    #pragma unroll
    for (int ks = 0; ks < 2; ++ks) {
      u16x8 pf = *(const u16x8*)&myP[arow*64 + ((ks*32 + kgrp*8 + 8*arow) & 63)];
      #pragma unroll
      for (int nt = 0; nt < 2; ++nt) {
        u16x8 vf = *(const u16x8*)&Vt[(hh*32 + nt*16 + arow)*72 + ks*32 + kgrp*8];
        oacc[nt] = mfma16(pf, vf, oacc[nt]);
      }
    }
    __builtin_amdgcn_s_setprio(0);
    #pragma unroll
    for (int nt = 0; nt < 2; ++nt)
      #pragma unroll
      for (int r = 0; r < 4; ++r)
        og[g][nt][r] = f2bf(oacc[nt][r]);
    __syncthreads();   // end-g: next QKV overwrites G/Vt
  }

  // ---- O (regs) -> Xs (swizzled) ----
  #pragma unroll
  for (int g = 0; g < 3; ++g)
    #pragma unroll
    for (int nt = 0; nt < 2; ++nt) {
      const int colb = g*64 + hh*32 + nt*16 + arow;
      #pragma unroll
      for (int r = 0; r < 4; ++r) {
        const int row = mt*16 + kgrp*4 + r;
        Xs[row*200 + (swz(row, colb>>3)<<3) + (colb&7)] = og[g][nt][r];
      }
    }
  __syncthreads();

  // ---- proj GEMM -> Pout [ch][tok] ----
  for (int nt0 = wave; nt0 < 12; nt0 += 8) {
    const int ch = nt0*16 + arow;
    const float pb = projb[ch];
    f32x4 acc[4];
    #pragma unroll
    for (int m = 0; m < 4; ++m) { f32x4 v = {pb,pb,pb,pb}; acc[m] = v; }
    const u16* wrow = wp + ch*192 + kgrp*8;
    __builtin_amdgcn_s_setprio(1);
    #pragma unroll
    for (int ks = 0; ks < 6; ++ks) {
      u16x8 bfr = *(const u16x8*)(wrow + ks*32);
      #pragma unroll
      for (int m = 0; m < 4; ++m) {
        const int row = m*16 + arow;
        u16x8 af = *(const u16x8*)&Xs[row*200 + (swz(row, ks*4 + kgrp)<<3)];
        acc[m] = mfma16(af, bfr, acc[m]);
      }
    }
    __builtin_amdgcn_s_setprio(0);
    #pragma unroll
    for (int m = 0; m < 4; ++m) {
      u16x4 pk;
      #pragma unroll
      for (int r = 0; r < 4; ++r) pk[r] = f2bf(acc[m][r]);
      *(u16x4*)&Pout[ch*72 + m*16 + kgrp*4] = pk;
    }
  }
  __syncthreads();

  // ---- epilogue: v = x + proj; bf16 v -> pw [wid][c][64tok]; stats2 partials ----
  u16* dstw = pw + (long)wid*12288;
  #pragma unroll
  for (int it = 0; it < 6; ++it) {
    const int c = it*32 + cbase;
    u16x4 pv = *(const u16x4*)&Pout[c*72 + tok0];
    float v0 = bf2f(xr[it][0]) + bf2f(pv[0]);
    float v1 = bf2f(xr[it][1]) + bf2f(pv[1]);
    float v2 = bf2f(xr[it][2]) + bf2f(pv[2]);
    float v3 = bf2f(xr[it][3]) + bf2f(pv[3]);
    u16x4 vb;
    vb[0] = f2bf(v0); vb[1] = f2bf(v1); vb[2] = f2bf(v2); vb[3] = f2bf(v3);
    *(u16x4*)(dstw + c*64 + tok0) = vb;
    float s  = v0 + v1 + v2 + v3;
    float ss = v0*v0 + v1*v1 + v2*v2 + v3*v3;
    for (int off = 1; off < 16; off <<= 1) {
      s  += __shfl_xor(s,  off, 64);
      ss += __shfl_xor(ss, off, 64);
    }
    if ((lane & 15) == 0) {
      atomicAdd(&st2[(b*192+c)*2],     s);
      atomicAdd(&st2[(b*192+c)*2 + 1], ss);
    }
  }
}

// ---- final: out = v + FiLM(norm2(v)); gathers window-major v, full-line writes ----
__global__ __launch_bounds__(256) void final_kernel(
    const u16* __restrict__ pw, const float* __restrict__ st2,
    const float* __restrict__ gb, float* __restrict__ out)
{
  __shared__ u16 tile[32*264];
  const int t = threadIdx.x;
  const int bid = blockIdx.x;
  const int lin = (bid & 7)*768 + (bid >> 3);      // XCD-contiguous row bands
  const int cc = lin % 6;
  const int rowid = lin / 6;
  const int gy = rowid & 255;
  const int b  = rowid >> 8;
  const int c0 = cc*32;
  const int gys = (gy + 252) & 255;                // gy - 4
  const int wh = gys >> 3, ay = gys & 7;

  // phase A: gather v for this output row
  {
    const int ww = t >> 3, cq = t & 7;
    const long wid = b*1024 + wh*32 + ww;
    const u16* srcw = pw + wid*12288;
    const int g1 = ww*8 + 4, g2 = (ww*8 + 8) & 255;
    #pragma unroll
    for (int j = 0; j < 4; ++j) {
      const int c = cq*4 + j;
      u16x8 v = *(const u16x8*)(srcw + (c0+c)*64 + ay*8);
      const int sw = (c & 7) << 2;
      u16x4 lo = {v[0],v[1],v[2],v[3]}, hi = {v[4],v[5],v[6],v[7]};
      *(u16x4*)&tile[c*264 + (g1 ^ sw)] = lo;
      *(u16x4*)&tile[c*264 + (g2 ^ sw)] = hi;
    }
  }
  __syncthreads();

  // phase B: out = v + (v-mean)*rstd*gamma + beta, full-line fp32 stores
  const int cl = t >> 3, seg = t & 7;
  const int c = c0 + cl;
  const float sm   = st2[(b*192+c)*2];
  const float ssum = st2[(b*192+c)*2 + 1];
  const float mean = sm * (1.f/PLANE);
  const float var  = ssum * (1.f/PLANE) - mean*mean;
  const float rstd = rsqrtf(var + 1e-5f);
  const float gmm  = gb[b*384 + c];
  const float be   = gb[b*384 + 192 + c];
  const long base = (((long)(b*192 + c)) << 16) + gy*256 + seg*32;
  float* orow = out + base;
  const int sw = (cl & 7) << 2;
  #pragma unroll
  for (int q4 = 0; q4 < 32; q4 += 4) {
    const int px = seg*32 + q4;
    u16x4 pv = *(const u16x4*)&tile[cl*264 + (px ^ sw)];
    float4 o;
    float v0 = bf2f(pv[0]), v1 = bf2f(pv[1]), v2 = bf2f(pv[2]), v3 = bf2f(pv[3]);
    o.x = v0 + (v0 - mean)*rstd*gmm + be;
    o.y = v1 + (v1 - mean)*rstd*gmm + be;
    o.z = v2 + (v2 - mean)*rstd*gmm + be;
    o.w = v3 + (v3 - mean)*rstd*gmm + be;
    *(float4*)(orow + q4) = o;
  }
}

extern "C" void kernel_launch(void* const* d_in, const int* in_sizes, int n_in,
                              void* d_out, int out_size, void* d_ws, size_t ws_size,
                              hipStream_t stream) {
  const float* x      = (const float*)d_in[0];
  const float* cond   = (const float*)d_in[1];
  const float* qkv_w  = (const float*)d_in[2];
  const float* qkv_b  = (const float*)d_in[3];
  const float* proj_w = (const float*)d_in[4];
  const float* proj_b = (const float*)d_in[5];
  const float* relb   = (const float*)d_in[6];
  const float* film_w = (const float*)d_in[7];
  const float* film_b = (const float*)d_in[8];
  float* out = (float*)d_out;

  char* ws = (char*)d_ws;
  float* stats1 = (float*)ws;                    // 768*2 f32
  float* st2    = (float*)(ws + 6144);           // 768*2 f32 (sum, sumsq)
  float* gb     = (float*)(ws + 12288);          // 4*384 f32
  u16*   wq     = (u16*)(ws + 18432);            // 576*192 bf16
  u16*   wp     = (u16*)(ws + 239616);           // 192*192 bf16
  u16*   bias6  = (u16*)(ws + 313344);           // 6*64*64 bf16
  u16*   pw     = (u16*)(ws + 362496);           // 4096*192*64 bf16 (v)

  stats_kernel<<<768, 256, 0, stream>>>(x, stats1);
  cvt_kernel<<<432, 256, 0, stream>>>(qkv_w, proj_w, relb, wq, wp, bias6);
  film_prep<<<6, 256, 0, stream>>>(cond, film_w, film_b, gb, st2);
  attn_kernel<<<4096, 512, 0, stream>>>(x, stats1, wq, wp, qkv_b, proj_b, bias6, pw, st2);
  final_kernel<<<6144, 256, 0, stream>>>(pw, st2, gb, out);
}